// Round 2
// baseline (226014.624 us; speedup 1.0000x reference)
//
#include <hip/hip_runtime.h>
#include <cmath>

// ---------------------------------------------------------------------------
// LPCNet-style vocoder on MI355X — full-fp32 AR path (round 2).
// (A) FrameRateNet + gi_cond hoist (parallel, tiny)
// (W) transpose out_w -> owT fp32
// (B) AR loop: 8 workgroups (1 per batch, zero cross-CU sync), 1024 threads,
//     W_h + out_w^T held in VGPRs as fp32 (256 regs/thread), h fp32 in
//     skew-padded LDS, fp32 FMA matvec, shuffle argmax, mu-law + de-emph.
// ---------------------------------------------------------------------------

#define NB 8
#define NF 64
#define ND 20
#define NH 256
#define NG 768      // 3*NH
#define FS 160
#define NT (NF * FS)   // 10240

// ---------------------------------------------------------------------------
// Kernel A: FrameRateNet (conv-tanh x2, fc-tanh x2) + gi_cond precompute.
// One block per (b, f). 128 threads (one per channel).
// gi_cond[b*64+f][j] = gru_bi[j] + sum_c cond[c] * gru_wi[j][1+c]
// ---------------------------------------------------------------------------
__global__ __launch_bounds__(128) void frn_kernel(
    const float* __restrict__ feat,   // (8,64,20)
    const float* __restrict__ w1,     // (3,20,128)
    const float* __restrict__ b1,
    const float* __restrict__ w2,     // (3,128,128)
    const float* __restrict__ b2,
    const float* __restrict__ fw1,    // (128,128)
    const float* __restrict__ fb1,
    const float* __restrict__ fw2,    // (128,128)
    const float* __restrict__ fb2,
    const float* __restrict__ wi,     // (768,129)
    const float* __restrict__ bi,     // (768,)
    float* __restrict__ gic)          // (8*64, 768)
{
    const int bf = blockIdx.x;
    const int b = bf >> 6;
    const int f = bf & 63;
    const int o = threadIdx.x;   // 0..127

    __shared__ float sfeat[5][ND];   // frames f-2..f+2, zero padded
    __shared__ float sc1[3][128];    // conv1 outputs at f-1..f+1 (zero if OOB)
    __shared__ float sc2[128];
    __shared__ float sc3[128];
    __shared__ float scond[128];

    for (int i = o; i < 5 * ND; i += 128) {
        int ff = f - 2 + i / ND;
        int c = i % ND;
        sfeat[i / ND][c] = (ff >= 0 && ff < NF) ? feat[((size_t)b * NF + ff) * ND + c] : 0.f;
    }
    __syncthreads();

    // conv1 (K=3, same pad) at frames f-1+df, df in 0..2
    for (int df = 0; df < 3; ++df) {
        int fp = f - 1 + df;
        if (fp >= 0 && fp < NF) {
            float acc = b1[o];
            for (int k = 0; k < 3; ++k)
                for (int c = 0; c < ND; ++c)
                    acc += sfeat[df + k][c] * w1[(k * ND + c) * 128 + o];
            sc1[df][o] = tanhf(acc);
        } else {
            sc1[df][o] = 0.f;   // zero-pad of conv2's input
        }
    }
    __syncthreads();

    {   // conv2 at f
        float acc = b2[o];
        for (int k = 0; k < 3; ++k)
            for (int c = 0; c < 128; ++c)
                acc += sc1[k][c] * w2[(k * 128 + c) * 128 + o];
        sc2[o] = tanhf(acc);
    }
    __syncthreads();
    {   // fc1
        float acc = fb1[o];
        for (int c = 0; c < 128; ++c) acc += sc2[c] * fw1[c * 128 + o];
        sc3[o] = tanhf(acc);
    }
    __syncthreads();
    {   // fc2 -> cond
        float acc = fb2[o];
        for (int c = 0; c < 128; ++c) acc += sc3[c] * fw2[c * 128 + o];
        scond[o] = tanhf(acc);
    }
    __syncthreads();

    // gi_cond rows j = o + 128*r
    for (int r = 0; r < 6; ++r) {
        int j = o + 128 * r;
        float acc = bi[j];
        const float* wr = wi + (size_t)j * 129 + 1;
        for (int c = 0; c < 128; ++c) acc += scond[c] * wr[c];
        gic[(size_t)bf * NG + j] = acc;
    }
}

// ---------------------------------------------------------------------------
// Kernel W: transpose out_w (c,o) -> owT (o,c), fp32.
// ---------------------------------------------------------------------------
__global__ __launch_bounds__(256) void wconv_kernel(
    const float* __restrict__ ow,    // (256,256) [c][o]
    float* __restrict__ owT)         // (256,256) [o][c]
{
    int i = blockIdx.x * 256 + threadIdx.x;
    int o = i >> 8, c = i & 255;
    owT[o * NH + c] = ow[c * NH + o];
}

// ---------------------------------------------------------------------------
// Kernel B: autoregressive GRU + greedy mu-law + de-emphasis. Full fp32.
// grid = 8 (one block per batch), block = 1024.
// Thread t: rb = t>>2 owns gh rows rb*3..rb*3+2, cc = t&3 owns cols cc*64..+63.
//           For logits: o = t&255, kq = t>>8 owns cols kq*64..+63.
// ---------------------------------------------------------------------------
#define HSTRIDE 68   // 64 + 4 pad floats per h-group: group bases hit banks 0/4/8/12

__global__ __launch_bounds__(1024) void ar_kernel(
    const float* __restrict__ gic,    // (8*64, 768) : bi + cond @ wi[:,1:]^T
    const float* __restrict__ wh,     // (768,256) fp32 row-major
    const float* __restrict__ owT,    // (256,256) fp32 o-major
    const float* __restrict__ wi,     // (768,129) -- need column 0
    const float* __restrict__ bh,     // (768,)
    const float* __restrict__ ob,     // (256,)
    float* __restrict__ wav_out,      // (8, 10240)
    float* __restrict__ logits_out)   // (8, 10240, 256)
{
    const int b = blockIdx.x;
    const int t = threadIdx.x;
    const int rb = t >> 2;
    const int cc = t & 3;

    // --- LDS state ---
    __shared__ __align__(16) float hsp[4 * HSTRIDE];  // h fp32, skew-padded groups
    __shared__ float pgh[4][NG + 8];                  // gh partials per col-chunk
    __shared__ float pl[4][NH + 8];                   // logits partials per col-quarter
    __shared__ float candv[4];
    __shared__ int   candi[4];
    __shared__ float sprev;

    // --- register-resident fp32 weights ---
    // wrow[r][k4]: row rb*3+r of W_h, cols cc*64 + 4*k4 .. +3
    float4 wrow[3][16];
    {
        const float* base = wh + (size_t)(rb * 3) * NH + cc * 64;
        #pragma unroll
        for (int r = 0; r < 3; ++r) {
            const float4* p = (const float4*)(base + r * NH);
            #pragma unroll
            for (int k = 0; k < 16; ++k) wrow[r][k] = p[k];
        }
    }
    // owv[k4]: out_w^T row (t&255), cols (t>>8)*64 + 4*k4 .. +3
    float4 owv[16];
    {
        const int o = t & 255, kq = t >> 8;
        const float4* p = (const float4*)(owT + (size_t)o * NH + kq * 64);
        #pragma unroll
        for (int k = 0; k < 16; ++k) owv[k] = p[k];
    }

    // per-thread scalars for gate / output phases
    float bh_r = 0, bh_z = 0, bh_n = 0, wi_r = 0, wi_z = 0, wi_n = 0, ob_o = 0;
    if (t < NH) {
        bh_r = bh[t]; bh_z = bh[t + 256]; bh_n = bh[t + 512];
        wi_r = wi[(size_t)t * 129];
        wi_z = wi[(size_t)(t + 256) * 129];
        wi_n = wi[(size_t)(t + 512) * 129];
        ob_o = ob[t];
    }

    if (t < NH) hsp[(t >> 6) * HSTRIDE + (t & 63)] = 0.f;
    if (t == 0) sprev = 0.f;
    float yacc = 0.f;
    __syncthreads();

    const float* gicb = gic + (size_t)b * NF * NG;
    float* lob = logits_out + (size_t)b * NT * NH;
    float* wob = wav_out + (size_t)b * NT;

    for (int st = 0; st < NT; ++st) {
        // ---- P1: gh partials: rows rb*3+{0,1,2}, cols cc*64..cc*64+63 ----
        {
            const float4* hv = (const float4*)hsp;   // group cc at float4 index cc*17
            float a0 = 0.f, a1 = 0.f, a2 = 0.f;
            #pragma unroll
            for (int k4 = 0; k4 < 16; ++k4) {
                float4 hq = hv[cc * (HSTRIDE / 4) + k4];
                a0 += wrow[0][k4].x * hq.x; a0 += wrow[0][k4].y * hq.y;
                a0 += wrow[0][k4].z * hq.z; a0 += wrow[0][k4].w * hq.w;
                a1 += wrow[1][k4].x * hq.x; a1 += wrow[1][k4].y * hq.y;
                a1 += wrow[1][k4].z * hq.z; a1 += wrow[1][k4].w * hq.w;
                a2 += wrow[2][k4].x * hq.x; a2 += wrow[2][k4].y * hq.y;
                a2 += wrow[2][k4].z * hq.z; a2 += wrow[2][k4].w * hq.w;
            }
            pgh[cc][rb * 3 + 0] = a0;
            pgh[cc][rb * 3 + 1] = a1;
            pgh[cc][rb * 3 + 2] = a2;
        }
        __syncthreads();

        // ---- P2: gates + h update (threads 0..255) ----
        if (t < NH) {
            const float* gf = gicb + (size_t)(st / FS) * NG;
            float prev = sprev;
            float hold = hsp[(t >> 6) * HSTRIDE + (t & 63)];
            float sr = gf[t] + wi_r * prev + bh_r
                     + pgh[0][t] + pgh[1][t] + pgh[2][t] + pgh[3][t];
            float sz = gf[t + 256] + wi_z * prev + bh_z
                     + pgh[0][t + 256] + pgh[1][t + 256] + pgh[2][t + 256] + pgh[3][t + 256];
            float ni = gf[t + 512] + wi_n * prev;
            float nh = bh_n
                     + pgh[0][t + 512] + pgh[1][t + 512] + pgh[2][t + 512] + pgh[3][t + 512];
            float r = 1.f / (1.f + expf(-sr));
            float z = 1.f / (1.f + expf(-sz));
            float n = tanhf(ni + r * nh);
            float hn = (1.f - z) * n + z * hold;
            hsp[(t >> 6) * HSTRIDE + (t & 63)] = hn;
        }
        __syncthreads();

        // ---- P3: logits partials: o = t&255, cols kq*64..+63 ----
        {
            const int o = t & 255, kq = t >> 8;
            const float4* hv = (const float4*)hsp;
            float a = 0.f;
            #pragma unroll
            for (int k4 = 0; k4 < 16; ++k4) {
                float4 hq = hv[kq * (HSTRIDE / 4) + k4];   // wave-uniform -> broadcast
                a += owv[k4].x * hq.x; a += owv[k4].y * hq.y;
                a += owv[k4].z * hq.z; a += owv[k4].w * hq.w;
            }
            pl[kq][o] = a;
        }
        __syncthreads();

        // ---- P4: finalize logits, store, per-wave argmax (first-max ties) ----
        if (t < NH) {
            float lg = ob_o + pl[0][t] + pl[1][t] + pl[2][t] + pl[3][t];
            lob[(size_t)st * NH + t] = lg;
            float bv = lg; int bidx = t;
            #pragma unroll
            for (int d = 32; d > 0; d >>= 1) {
                float ov = __shfl_down(bv, d);
                int   oi = __shfl_down(bidx, d);
                if (ov > bv || (ov == bv && oi < bidx)) { bv = ov; bidx = oi; }
            }
            if ((t & 63) == 0) { candv[t >> 6] = bv; candi[t >> 6] = bidx; }
        }
        __syncthreads();

        // ---- P5: pick winner, mu-law expand, de-emphasis, feedback ----
        if (t == 0) {
            float bv = candv[0]; int bidx = candi[0];
            #pragma unroll
            for (int w = 1; w < 4; ++w) {
                float ov = candv[w]; int oi = candi[w];
                if (ov > bv || (ov == bv && oi < bidx)) { bv = ov; bidx = oi; }
            }
            float v = ((float)bidx + 0.5f) * (1.f / 128.f) - 1.f;
            float av = fabsf(v);
            float mag = (exp2f(8.f * av) - 1.f) * (1.f / 255.f);  // (256^|v|-1)/255
            float smp = (v >= 0.f) ? mag : -mag;
            sprev = smp;
            yacc = smp + 0.97f * yacc;
            wob[st] = yacc;
        }
        __syncthreads();
    }
}

// ---------------------------------------------------------------------------
extern "C" void kernel_launch(void* const* d_in, const int* in_sizes, int n_in,
                              void* d_out, int out_size, void* d_ws, size_t ws_size,
                              hipStream_t stream) {
    (void)in_sizes; (void)n_in; (void)out_size; (void)ws_size;

    const float* feat = (const float*)d_in[0];
    const float* c1w  = (const float*)d_in[1];
    const float* c1b  = (const float*)d_in[2];
    const float* c2w  = (const float*)d_in[3];
    const float* c2b  = (const float*)d_in[4];
    const float* f1w  = (const float*)d_in[5];
    const float* f1b  = (const float*)d_in[6];
    const float* f2w  = (const float*)d_in[7];
    const float* f2b  = (const float*)d_in[8];
    const float* gwi  = (const float*)d_in[9];
    const float* gwh  = (const float*)d_in[10];
    const float* gbi  = (const float*)d_in[11];
    const float* gbh  = (const float*)d_in[12];
    const float* outw = (const float*)d_in[13];
    const float* outb = (const float*)d_in[14];

    // workspace layout
    float* gic = (float*)d_ws;                          // 8*64*768 fp32 = 1572864 B
    float* owT = (float*)((char*)d_ws + 1572864);       // 256*256 fp32  = 262144 B

    float* wav    = (float*)d_out;                 // (8,10240,1)
    float* logits = (float*)d_out + NB * NT;       // (8,10240,256)

    frn_kernel<<<dim3(NB * NF), dim3(128), 0, stream>>>(
        feat, c1w, c1b, c2w, c2b, f1w, f1b, f2w, f2b, gwi, gbi, gic);
    wconv_kernel<<<dim3(256), dim3(256), 0, stream>>>(outw, owT);
    ar_kernel<<<dim3(NB), dim3(1024), 0, stream>>>(
        gic, gwh, owT, gwi, gbh, outb, wav, logits);
}

// Round 3
// 103871.985 us; speedup vs baseline: 2.1759x; 2.1759x over previous
//
#include <hip/hip_runtime.h>
#include <cmath>

// ---------------------------------------------------------------------------
// LPCNet-style vocoder on MI355X — round 3: 2-CU-per-batch row-split AR loop.
// R2 post-mortem: VGPR_Count=64 -> compiler sank weight loads; every step
// re-streamed ~1MB from L2 (22us/step). fp32 weights can't fit one CU
// (1.05MB > 512KB regfile + 160KB LDS), so split each batch across TWO CUs:
//   block k of pair owns W_h rows {q, q+256, q+512 : q in [128k,128k+128)}
//   full-K (192 VGPRs/thread, pinned via asm) -> computes its OWN half of
//   h_new with NO gh exchange. Per step only: 128-float h-half exchange +
//   8-byte argmax-max exchange (LLC flag protocol, agent-scope atomics,
//   parity double-buffered). Logits: o-half full-K, out_w streamed
//   coalesced from L2 (131KB/step, the only remaining stream).
// ---------------------------------------------------------------------------

#define NB 8
#define NF 64
#define ND 20
#define NH 256
#define NG 768      // 3*NH
#define FS 160
#define NT (NF * FS)   // 10240

#define AGENT __HIP_MEMORY_SCOPE_AGENT

__device__ __forceinline__ void st_ag(float* p, float v) {
    __hip_atomic_store(p, v, __ATOMIC_RELAXED, AGENT);
}
__device__ __forceinline__ float ld_ag(float* p) {
    return __hip_atomic_load(p, __ATOMIC_RELAXED, AGENT);
}
__device__ __forceinline__ void st_ag_i(int* p, int v) {
    __hip_atomic_store(p, v, __ATOMIC_RELAXED, AGENT);
}
__device__ __forceinline__ int ld_ag_i(int* p) {
    return __hip_atomic_load(p, __ATOMIC_RELAXED, AGENT);
}

// ---------------------------------------------------------------------------
// Kernel A: FrameRateNet (conv-tanh x2, fc-tanh x2) + gi_cond precompute.
// (unchanged from R2 — passing, runs in parallel, ~us scale)
// ---------------------------------------------------------------------------
__global__ __launch_bounds__(128) void frn_kernel(
    const float* __restrict__ feat,
    const float* __restrict__ w1,
    const float* __restrict__ b1,
    const float* __restrict__ w2,
    const float* __restrict__ b2,
    const float* __restrict__ fw1,
    const float* __restrict__ fb1,
    const float* __restrict__ fw2,
    const float* __restrict__ fb2,
    const float* __restrict__ wi,
    const float* __restrict__ bi,
    float* __restrict__ gic)
{
    const int bf = blockIdx.x;
    const int b = bf >> 6;
    const int f = bf & 63;
    const int o = threadIdx.x;

    __shared__ float sfeat[5][ND];
    __shared__ float sc1[3][128];
    __shared__ float sc2[128];
    __shared__ float sc3[128];
    __shared__ float scond[128];

    for (int i = o; i < 5 * ND; i += 128) {
        int ff = f - 2 + i / ND;
        int c = i % ND;
        sfeat[i / ND][c] = (ff >= 0 && ff < NF) ? feat[((size_t)b * NF + ff) * ND + c] : 0.f;
    }
    __syncthreads();

    for (int df = 0; df < 3; ++df) {
        int fp = f - 1 + df;
        if (fp >= 0 && fp < NF) {
            float acc = b1[o];
            for (int k = 0; k < 3; ++k)
                for (int c = 0; c < ND; ++c)
                    acc += sfeat[df + k][c] * w1[(k * ND + c) * 128 + o];
            sc1[df][o] = tanhf(acc);
        } else {
            sc1[df][o] = 0.f;
        }
    }
    __syncthreads();

    {
        float acc = b2[o];
        for (int k = 0; k < 3; ++k)
            for (int c = 0; c < 128; ++c)
                acc += sc1[k][c] * w2[(k * 128 + c) * 128 + o];
        sc2[o] = tanhf(acc);
    }
    __syncthreads();
    {
        float acc = fb1[o];
        for (int c = 0; c < 128; ++c) acc += sc2[c] * fw1[c * 128 + o];
        sc3[o] = tanhf(acc);
    }
    __syncthreads();
    {
        float acc = fb2[o];
        for (int c = 0; c < 128; ++c) acc += sc3[c] * fw2[c * 128 + o];
        scond[o] = tanhf(acc);
    }
    __syncthreads();

    for (int r = 0; r < 6; ++r) {
        int j = o + 128 * r;
        float acc = bi[j];
        const float* wr = wi + (size_t)j * 129 + 1;
        for (int c = 0; c < 128; ++c) acc += scond[c] * wr[c];
        gic[(size_t)bf * NG + j] = acc;
    }
}

// ---------------------------------------------------------------------------
// Kernel B: AR loop, 16 blocks (pair = bid^8 -> likely same XCD), 512 thr.
// ---------------------------------------------------------------------------
__global__ __launch_bounds__(512, 2) void ar_kernel(
    const float* __restrict__ gic,    // (8*64, 768)
    const float* __restrict__ wh,     // (768,256) fp32
    const float* __restrict__ ow,     // (256,256) [c][o] — native layout, coalesced over o
    const float* __restrict__ wi,     // (768,129)
    const float* __restrict__ bh,     // (768,)
    const float* __restrict__ ob,     // (256,)
    float* __restrict__ wav_out,      // (8, 10240)
    float* __restrict__ logits_out,   // (8, 10240, 256)
    int* flagH, int* flagM,           // [16] each
    float* hx,                        // [16][2][128]
    float* xmv, int* xmi)             // [16][2]
{
    const int bid = blockIdx.x;
    const int b = bid & 7;            // batch
    const int k = bid >> 3;           // half (partner = bid ^ 8)
    const int t = threadIdx.x;
    const int qq = t >> 2;            // 0..127 : local hidden unit
    const int ss = t & 3;             // K-quarter (64 cols)

    __shared__ float hs[NH];                    // full h (both halves)
    __shared__ float pgh[4][388];               // [ss][qq*3+r]; 388 pad spreads banks
    __shared__ __align__(16) float pls[16][128];// [c-chunk][local o]
    __shared__ float candv[2];
    __shared__ int   candi[2];
    __shared__ float sprev;

    // ---- register-resident W_h rows (full K), pinned against load-sinking ----
    float4 w0[16], w1[16], w2[16];
    {
        const float4* wb = (const float4*)wh;           // row = 64 float4
        size_t base = (size_t)(128 * k + qq) * 64 + ss * 16;
        #pragma unroll
        for (int i = 0; i < 16; ++i) {
            w0[i] = wb[base + i];
            w1[i] = wb[base + 256 * 64 + i];
            w2[i] = wb[base + 512 * 64 + i];
        }
    }
    #pragma unroll
    for (int i = 0; i < 16; ++i) {
        asm volatile("" : "+v"(w0[i].x), "+v"(w0[i].y), "+v"(w0[i].z), "+v"(w0[i].w));
        asm volatile("" : "+v"(w1[i].x), "+v"(w1[i].y), "+v"(w1[i].z), "+v"(w1[i].w));
        asm volatile("" : "+v"(w2[i].x), "+v"(w2[i].y), "+v"(w2[i].z), "+v"(w2[i].w));
    }

    // ---- per-thread gate/output scalars (threads 0..127 = own hidden half) ----
    float bh_r = 0, bh_z = 0, bh_n = 0, wi_r = 0, wi_z = 0, wi_n = 0, ob_o = 0;
    if (t < 128) {
        int gr = 128 * k + t;
        bh_r = bh[gr]; bh_z = bh[gr + 256]; bh_n = bh[gr + 512];
        wi_r = wi[(size_t)gr * 129];
        wi_z = wi[(size_t)(gr + 256) * 129];
        wi_n = wi[(size_t)(gr + 512) * 129];
        ob_o = ob[gr];
    }

    if (t < NH) hs[t] = 0.f;
    if (t == 0) sprev = 0.f;
    float yacc = 0.f;
    __syncthreads();

    const float* gicb = gic + (size_t)b * NF * NG;
    float* lob = logits_out + (size_t)b * NT * NH;
    float* wob = wav_out + (size_t)b * NT;

    for (int st = 0; st <= NT; ++st) {
        // ---- Phase A: P1_st (gh partials from h_{st-1}) + P3_{st-1} (logits) ----
        if (st < NT) {
            const float4* h4 = (const float4*)hs;
            float a0 = 0.f, a1 = 0.f, a2 = 0.f;
            #pragma unroll
            for (int i = 0; i < 16; ++i) {
                float4 hv = h4[ss * 16 + i];
                a0 += w0[i].x * hv.x + w0[i].y * hv.y + w0[i].z * hv.z + w0[i].w * hv.w;
                a1 += w1[i].x * hv.x + w1[i].y * hv.y + w1[i].z * hv.z + w1[i].w * hv.w;
                a2 += w2[i].x * hv.x + w2[i].y * hv.y + w2[i].z * hv.z + w2[i].w * hv.w;
            }
            pgh[ss][qq * 3 + 0] = a0;
            pgh[ss][qq * 3 + 1] = a1;
            pgh[ss][qq * 3 + 2] = a2;
        }
        if (st > 0) {
            // logits o-half [128k,+128), full K; out_w native [c][o] coalesced
            const int oq = t & 31, cc = t >> 5;
            const float4* owp = (const float4*)ow;      // row c = 64 float4
            float4 acc = {0.f, 0.f, 0.f, 0.f};
            #pragma unroll
            for (int j = 0; j < 16; ++j) {
                int c = cc * 16 + j;
                float4 wv = owp[(size_t)c * 64 + 32 * k + oq];
                float hc = hs[c];
                acc.x += wv.x * hc; acc.y += wv.y * hc;
                acc.z += wv.z * hc; acc.w += wv.w * hc;
            }
            *(float4*)&pls[cc][oq * 4] = acc;
        }
        __syncthreads();

        // ---- Phase B: finalize local logits + store + local argmax ----
        if (st > 0 && t < 128) {
            float lg = ob_o;
            #pragma unroll
            for (int cc2 = 0; cc2 < 16; ++cc2) lg += pls[cc2][t];
            lob[(size_t)(st - 1) * NH + 128 * k + t] = lg;
            float bv = lg; int bi_ = 128 * k + t;
            #pragma unroll
            for (int d = 32; d > 0; d >>= 1) {
                float ov = __shfl_down(bv, d);
                int   oi = __shfl_down(bi_, d);
                if (ov > bv || (ov == bv && oi < bi_)) { bv = ov; bi_ = oi; }
            }
            if ((t & 63) == 0) { candv[t >> 6] = bv; candi[t >> 6] = bi_; }
        }
        __syncthreads();

        // ---- Phase C: cross-CU max exchange + mu-law sample + de-emphasis ----
        if (st > 0 && t == 0) {
            float mv = candv[0]; int mi = candi[0];
            if (candv[1] > mv || (candv[1] == mv && candi[1] < mi)) { mv = candv[1]; mi = candi[1]; }
            int slot = (st - 1) & 1;
            st_ag(&xmv[bid * 2 + slot], mv);
            st_ag_i(&xmi[bid * 2 + slot], mi);
            __hip_atomic_store(&flagM[bid], st, __ATOMIC_RELEASE, AGENT);
            while (__hip_atomic_load(&flagM[bid ^ 8], __ATOMIC_ACQUIRE, AGENT) < st)
                __builtin_amdgcn_s_sleep(1);
            float rv = ld_ag(&xmv[(bid ^ 8) * 2 + slot]);
            int   ri = ld_ag_i(&xmi[(bid ^ 8) * 2 + slot]);
            if (rv > mv || (rv == mv && ri < mi)) { mv = rv; mi = ri; }
            float v = ((float)mi + 0.5f) * (1.f / 128.f) - 1.f;
            float av = fabsf(v);
            float mag = (exp2f(8.f * av) - 1.f) * (1.f / 255.f);
            float smp = (v >= 0.f) ? mag : -mag;
            sprev = smp;
            yacc = smp + 0.97f * yacc;
            if (k == 0) wob[st - 1] = yacc;
        }
        __syncthreads();

        // ---- Phase D: gates (own half) + h-half exchange ----
        if (st < NT) {
            int slot = st & 1;
            if (t < 128) {
                int gr = 128 * k + t;
                const float* gf = gicb + (size_t)(st / FS) * NG;
                float prev = sprev;
                float s_r = pgh[0][t * 3 + 0] + pgh[1][t * 3 + 0] + pgh[2][t * 3 + 0] + pgh[3][t * 3 + 0];
                float s_z = pgh[0][t * 3 + 1] + pgh[1][t * 3 + 1] + pgh[2][t * 3 + 1] + pgh[3][t * 3 + 1];
                float s_n = pgh[0][t * 3 + 2] + pgh[1][t * 3 + 2] + pgh[2][t * 3 + 2] + pgh[3][t * 3 + 2];
                float sr = gf[gr]       + wi_r * prev + bh_r + s_r;
                float sz = gf[gr + 256] + wi_z * prev + bh_z + s_z;
                float ni = gf[gr + 512] + wi_n * prev;
                float nh = bh_n + s_n;
                float r = 1.f / (1.f + expf(-sr));
                float z = 1.f / (1.f + expf(-sz));
                float n = tanhf(ni + r * nh);
                float hold = hs[gr];
                float hn = (1.f - z) * n + z * hold;
                hs[gr] = hn;
                st_ag(&hx[(bid * 2 + slot) * 128 + t], hn);
            }
            __syncthreads();
            if (t == 0) {
                __threadfence();
                __hip_atomic_store(&flagH[bid], st + 1, __ATOMIC_RELEASE, AGENT);
                while (__hip_atomic_load(&flagH[bid ^ 8], __ATOMIC_ACQUIRE, AGENT) < st + 1)
                    __builtin_amdgcn_s_sleep(1);
            }
            __syncthreads();
            if (t < 128)
                hs[128 * (1 - k) + t] = ld_ag(&hx[((bid ^ 8) * 2 + slot) * 128 + t]);
            __syncthreads();
        }
    }
}

// ---------------------------------------------------------------------------
extern "C" void kernel_launch(void* const* d_in, const int* in_sizes, int n_in,
                              void* d_out, int out_size, void* d_ws, size_t ws_size,
                              hipStream_t stream) {
    (void)in_sizes; (void)n_in; (void)out_size; (void)ws_size;

    const float* feat = (const float*)d_in[0];
    const float* c1w  = (const float*)d_in[1];
    const float* c1b  = (const float*)d_in[2];
    const float* c2w  = (const float*)d_in[3];
    const float* c2b  = (const float*)d_in[4];
    const float* f1w  = (const float*)d_in[5];
    const float* f1b  = (const float*)d_in[6];
    const float* f2w  = (const float*)d_in[7];
    const float* f2b  = (const float*)d_in[8];
    const float* gwi  = (const float*)d_in[9];
    const float* gwh  = (const float*)d_in[10];
    const float* gbi  = (const float*)d_in[11];
    const float* gbh  = (const float*)d_in[12];
    const float* outw = (const float*)d_in[13];
    const float* outb = (const float*)d_in[14];

    // workspace layout
    char* ws = (char*)d_ws;
    float* gic  = (float*)ws;                        // 8*64*768 fp32 = 1,572,864 B
    int*  flagH = (int*)(ws + 1572864);              // 64 B
    int*  flagM = (int*)(ws + 1572864 + 64);         // 64 B
    float* hx   = (float*)(ws + 1572864 + 128);      // 16*2*128 fp32 = 16,384 B
    float* xmv  = (float*)(ws + 1572864 + 128 + 16384);   // 128 B
    int*  xmi   = (int*)(ws + 1572864 + 128 + 16384 + 128); // 128 B

    float* wav    = (float*)d_out;
    float* logits = (float*)d_out + NB * NT;

    // flags must be zeroed every call (ws is re-poisoned to 0xAA)
    hipMemsetAsync(ws + 1572864, 0, 128, stream);

    frn_kernel<<<dim3(NB * NF), dim3(128), 0, stream>>>(
        feat, c1w, c1b, c2w, c2b, f1w, f1b, f2w, f2b, gwi, gbi, gic);
    ar_kernel<<<dim3(16), dim3(512), 0, stream>>>(
        gic, gwh, outw, gwi, gbh, outb, wav, logits,
        flagH, flagM, hx, xmv, xmi);
}